// Round 6
// baseline (380.128 us; speedup 1.0000x reference)
//
#include <hip/hip_runtime.h>

// GraphConv 3-layer GCN: N=100000 nodes, E=1280000 edges; dims 128->64->64->40.
constexpr int NN = 100000;
constexpr int NE = 1280000;
constexpr int NP = 100352;       // padded N (= 98 * 1024)
constexpr int NBLK = NP / 1024;  // 98 scan chunks

// LDS-segmented histogram geometry.
// 64 KB LDS/block + 1024-thread blocks -> 2 blocks/CU = 32 waves/CU (full).
constexpr int SEGSZ = 16384;                  // 64 KB of int bins per block
constexpr int NSEG = 7;                       // 7*16384 = 114688 >= NN
constexpr int NCHUNK = 64;                    // edge chunks
constexpr int CHSZ = NE / NCHUNK;             // 20000 (exact)

// ---------------------------------------------------------------------------
// Histogram of vals[] (node ids) into partial[c][n] (stride NN), via LDS bins.
// ---------------------------------------------------------------------------
__global__ __launch_bounds__(1024) void hist_lds_kernel(
    const int* __restrict__ vals, int* __restrict__ partial) {
  __shared__ int hcnt[SEGSZ];
  const int s = blockIdx.x % NSEG, c = blockIdx.x / NSEG;
  const int t = threadIdx.x;
#pragma unroll 4
  for (int i = t; i < SEGSZ; i += 1024) hcnt[i] = 0;
  __syncthreads();
  const int lo = s * SEGSZ;
  const int beg = c * CHSZ;
  for (int e = beg + t; e < beg + CHSZ; e += 1024) {
    unsigned v = (unsigned)(vals[e] - lo);
    if (v < (unsigned)SEGSZ) atomicAdd(&hcnt[v], 1);  // LDS atomic
  }
  __syncthreads();
  int* p = partial + (size_t)c * NN;
#pragma unroll 4
  for (int i = t; i < SEGSZ; i += 1024) {
    int n = lo + i;
    if (n < NN) p[n] = hcnt[i];
  }
}

// ---------------------------------------------------------------------------
// Merge chunk-partials per node: cnt_in = sum, pin <- exclusive chunk prefix
// (in place, consumed by fill), norms from both degree sums.
// ---------------------------------------------------------------------------
__global__ __launch_bounds__(256) void merge_kernel(
    int* __restrict__ pin, const int* __restrict__ pout,
    int* __restrict__ cnt_in, float* __restrict__ norm_out,
    float* __restrict__ norm_in) {
  int n = blockIdx.x * 256 + threadIdx.x;
  if (n >= NN) return;
  int run = 0;
#pragma unroll 8
  for (int c = 0; c < NCHUNK; ++c) {
    size_t idx = (size_t)c * NN + n;
    int v = pin[idx];
    pin[idx] = run;
    run += v;
  }
  cnt_in[n] = run;
  int s = 0;
#pragma unroll 8
  for (int c = 0; c < NCHUNK; ++c) s += pout[(size_t)c * NN + n];
  norm_in[n]  = rsqrtf(fmaxf((float)run, 1.0f));
  norm_out[n] = rsqrtf(fmaxf((float)s, 1.0f));
}

// ---------------------------------------------------------------------------
// Two-level exclusive scan of cnt_in -> row_ptr
// ---------------------------------------------------------------------------
__global__ __launch_bounds__(256) void chunk_sum_kernel(
    const int* __restrict__ cnt, int* __restrict__ partial) {
  int t = threadIdx.x;
  int base = blockIdx.x * 1024 + t * 4;
  int s = 0;
#pragma unroll
  for (int j = 0; j < 4; ++j) {
    int gi = base + j;
    s += (gi < NN) ? cnt[gi] : 0;
  }
  __shared__ int r[256];
  r[t] = s;
  __syncthreads();
  for (int off = 128; off > 0; off >>= 1) {
    if (t < off) r[t] += r[t + off];
    __syncthreads();
  }
  if (t == 0) partial[blockIdx.x] = r[0];
}

__global__ __launch_bounds__(128) void partial_scan_kernel(int* __restrict__ partial) {
  int t = threadIdx.x;
  int v = (t < NBLK) ? partial[t] : 0;
  __shared__ int s[128];
  s[t] = v;
  __syncthreads();
  for (int off = 1; off < 128; off <<= 1) {
    int add = (t >= off) ? s[t - off] : 0;
    __syncthreads();
    s[t] += add;
    __syncthreads();
  }
  if (t < NBLK) partial[t] = s[t] - v;  // exclusive
}

__global__ __launch_bounds__(256) void chunk_scan_kernel(
    const int* __restrict__ cnt, const int* __restrict__ partial,
    int* __restrict__ row_ptr) {
  int t = threadIdx.x;
  int base = blockIdx.x * 1024 + t * 4;
  int c[4];
#pragma unroll
  for (int j = 0; j < 4; ++j) {
    int gi = base + j;
    c[j] = (gi < NN) ? cnt[gi] : 0;
  }
  int tsum = c[0] + c[1] + c[2] + c[3];
  __shared__ int s[256];
  s[t] = tsum;
  __syncthreads();
  for (int off = 1; off < 256; off <<= 1) {
    int add = (t >= off) ? s[t - off] : 0;
    __syncthreads();
    s[t] += add;
    __syncthreads();
  }
  int run = s[t] - tsum + partial[blockIdx.x];
#pragma unroll
  for (int j = 0; j < 4; ++j) {
    int gi = base + j;
    if (gi <= NN) row_ptr[gi] = run;
    run += c[j];
  }
}

// ---------------------------------------------------------------------------
// CSR fill via LDS cursors (no device atomics).
// ---------------------------------------------------------------------------
__global__ __launch_bounds__(1024) void fill_lds_kernel(
    const int* __restrict__ src, const int* __restrict__ dst,
    const int* __restrict__ row_ptr, const int* __restrict__ pin,
    int* __restrict__ csr_src) {
  __shared__ int cur[SEGSZ];
  const int s = blockIdx.x % NSEG, c = blockIdx.x / NSEG;
  const int t = threadIdx.x;
  const int lo = s * SEGSZ;
  const int* base = pin + (size_t)c * NN;
#pragma unroll 4
  for (int i = t; i < SEGSZ; i += 1024) {
    int n = lo + i;
    cur[i] = (n < NN) ? (row_ptr[n] + base[n]) : 0;
  }
  __syncthreads();
  const int beg = c * CHSZ;
  for (int e = beg + t; e < beg + CHSZ; e += 1024) {
    unsigned d = (unsigned)(dst[e] - lo);
    if (d < (unsigned)SEGSZ) {
      int pos = atomicAdd(&cur[d], 1);  // LDS atomic
      csr_src[pos] = src[e];
    }
  }
}

// ---------------------------------------------------------------------------
// GEMM: out[row,:] = PRE(in[row,:]) @ W  (PRE = *norm_out when SCALE)
// Tile 256 rows x 64 cols, 256 threads = 32 row-groups x 8 col-groups,
// 8x8 micro-tile -> 64 FMAs per 4 ds_read_b128 (2 FLOP/LDS-byte).
// x staged transposed with XOR swizzle (conflict-free transpose writes,
// b128-able reads); W staged per 32-K chunk (8 KB). LDS 41.5 KB.
// ---------------------------------------------------------------------------
template <int K, int COLS, bool SCALE>
__global__ __launch_bounds__(256) void gemm_kernel(
    const float* __restrict__ in, const float* __restrict__ W,
    const float* __restrict__ norm_out, float* __restrict__ out) {
  constexpr int KC = 32;
  constexpr int BM = 256;
  constexpr int XS = 260;  // 256 + 4 pad; 260*4B is 16B-aligned
  __shared__ float Wl[KC][64];
  __shared__ float xt[KC][XS];

  const int tid = threadIdx.x;
  const int tcg = tid & 7;    // col group: cols 8*tcg..8*tcg+7
  const int trg = tid >> 3;   // row group: rows 8*trg..8*trg+7
  const int row0 = blockIdx.x * BM;

  float acc[8][8] = {};

  for (int kc = 0; kc < K; kc += KC) {
    // Stage W chunk (coalesced, L2-hot; zero-pad cols >= COLS)
    for (int i = tid; i < KC * 64; i += 256) {
      int k = i >> 6, c = i & 63;
      Wl[k][c] = (c < COLS) ? W[(kc + k) * COLS + c] : 0.0f;
    }
    // Stage x chunk transposed: row r, float4 k4. Swizzle rs = r ^ ((k4&3)<<3)
    // spreads transpose writes over all banks (2-way max = free).
#pragma unroll
    for (int i = 0; i < 8; ++i) {
      int q = i * 256 + tid;
      int r = q >> 3;
      int k4 = q & 7;
      int grow = row0 + r;
      float4 v = {0.f, 0.f, 0.f, 0.f};
      if (grow < NN) {
        v = *(const float4*)&in[(size_t)grow * K + kc + 4 * k4];
        if constexpr (SCALE) {
          float no = norm_out[grow];
          v.x *= no; v.y *= no; v.z *= no; v.w *= no;
        }
      }
      int rs = r ^ ((k4 & 3) << 3);
      xt[4 * k4 + 0][rs] = v.x;
      xt[4 * k4 + 1][rs] = v.y;
      xt[4 * k4 + 2][rs] = v.z;
      xt[4 * k4 + 3][rs] = v.w;
    }
    __syncthreads();
#pragma unroll
    for (int kk = 0; kk < KC; ++kk) {
      int rb = (8 * trg) ^ ((((unsigned)kk >> 2) & 3) << 3);
      float4 x0 = *(const float4*)&xt[kk][rb];
      float4 x1 = *(const float4*)&xt[kk][rb + 4];
      float4 w0 = *(const float4*)&Wl[kk][8 * tcg];
      float4 w1 = *(const float4*)&Wl[kk][8 * tcg + 4];
      float xa[8] = {x0.x, x0.y, x0.z, x0.w, x1.x, x1.y, x1.z, x1.w};
      float wa[8] = {w0.x, w0.y, w0.z, w0.w, w1.x, w1.y, w1.z, w1.w};
#pragma unroll
      for (int r = 0; r < 8; ++r)
#pragma unroll
        for (int c = 0; c < 8; ++c)
          acc[r][c] = fmaf(xa[r], wa[c], acc[r][c]);
    }
    __syncthreads();
  }

  // Epilogue: 2 float4 stores per row (16B-aligned for COLS=64 and 40)
  if (8 * tcg < COLS) {
#pragma unroll
    for (int r = 0; r < 8; ++r) {
      int grow = row0 + 8 * trg + r;
      if (grow < NN) {
        float4 s0 = {acc[r][0], acc[r][1], acc[r][2], acc[r][3]};
        float4 s1 = {acc[r][4], acc[r][5], acc[r][6], acc[r][7]};
        float* o = &out[(size_t)grow * COLS + 8 * tcg];
        *(float4*)o = s0;
        *(float4*)(o + 4) = s1;
      }
    }
  }
}

// ---------------------------------------------------------------------------
// CSR gather, one wave per node, float4 lanes x 4-edge groups.
// ---------------------------------------------------------------------------
template <int C, bool RELU>
__global__ __launch_bounds__(256) void gather_kernel(
    const float* __restrict__ m, const int* __restrict__ row_ptr,
    const int* __restrict__ csr_src, const float* __restrict__ norm_in,
    const float* __restrict__ norm_out, const float* __restrict__ bias,
    float* __restrict__ outp) {
  constexpr int CV = C / 4;  // float4s per row: 16 (C=64), 10 (C=40)
  const int node = blockIdx.x * 4 + (threadIdx.x >> 6);
  const int lane = threadIdx.x & 63;
  if (node >= NN) return;
  const int beg = row_ptr[node];
  const int end = row_ptr[node + 1];
  const int eg = lane >> 4;
  const int fl = lane & 15;
  const float4* m4 = (const float4*)m;

  float4 acc = {0.f, 0.f, 0.f, 0.f};
#pragma unroll 4
  for (int i = beg + eg; i < end; i += 4) {
    int s = csr_src[i];
    if (fl < CV) {
      float4 v = m4[(size_t)s * CV + fl];
      acc.x += v.x; acc.y += v.y; acc.z += v.z; acc.w += v.w;
    }
  }
  acc.x += __shfl_xor(acc.x, 16); acc.y += __shfl_xor(acc.y, 16);
  acc.z += __shfl_xor(acc.z, 16); acc.w += __shfl_xor(acc.w, 16);
  acc.x += __shfl_xor(acc.x, 32); acc.y += __shfl_xor(acc.y, 32);
  acc.z += __shfl_xor(acc.z, 32); acc.w += __shfl_xor(acc.w, 32);

  if (eg == 0 && fl < CV) {
    float ni = norm_in[node];
    float4 b4 = ((const float4*)bias)[fl];
    float4 r;
    r.x = fmaf(acc.x, ni, b4.x);
    r.y = fmaf(acc.y, ni, b4.y);
    r.z = fmaf(acc.z, ni, b4.z);
    r.w = fmaf(acc.w, ni, b4.w);
    if constexpr (RELU) {
      float no = norm_out[node];
      r.x = fmaxf(r.x, 0.f) * no;
      r.y = fmaxf(r.y, 0.f) * no;
      r.z = fmaxf(r.z, 0.f) * no;
      r.w = fmaxf(r.w, 0.f) * no;
    }
    ((float4*)outp)[(size_t)node * CV + fl] = r;
  }
}

// ---------------------------------------------------------------------------
extern "C" void kernel_launch(void* const* d_in, const int* in_sizes, int n_in,
                              void* d_out, int out_size, void* d_ws, size_t ws_size,
                              hipStream_t stream) {
  const float* x    = (const float*)d_in[0];
  const float* W0   = (const float*)d_in[1];
  const float* b0   = (const float*)d_in[2];
  const float* W1   = (const float*)d_in[3];
  const float* b1   = (const float*)d_in[4];
  const float* W2   = (const float*)d_in[5];
  const float* b2   = (const float*)d_in[6];
  const int*   esrc = (const int*)d_in[7];
  const int*   edst = (const int*)d_in[8];
  float* out = (float*)d_out;

  // Workspace (4B units): norms/row_ptr/cnt_in/partial + csr_src[NE] +
  // m[NN*64] + h[NN*64]. CSR-build transients alias m/h (dead until gemm0):
  // pin = m (NCHUNK*NN = 25.6 MB exactly), pout = h.
  float* f        = (float*)d_ws;
  float* norm_out = f;
  float* norm_in  = f + NP;
  int*   row_ptr  = (int*)(f + 2 * NP);
  int*   cnt_in   = row_ptr + NP;
  int*   partial  = cnt_in + NP;
  int*   csr_src  = partial + 128;
  float* m        = (float*)(csr_src + NE);
  float* h        = m + NN * 64;
  int*   pin      = (int*)m;
  int*   pout     = (int*)h;

  // --- CSR build (dst-sorted) + norms: zero global atomics ---
  hist_lds_kernel<<<NSEG * NCHUNK, 1024, 0, stream>>>(edst, pin);
  hist_lds_kernel<<<NSEG * NCHUNK, 1024, 0, stream>>>(esrc, pout);
  merge_kernel<<<(NN + 255) / 256, 256, 0, stream>>>(pin, pout, cnt_in, norm_out, norm_in);
  chunk_sum_kernel<<<NBLK, 256, 0, stream>>>(cnt_in, partial);
  partial_scan_kernel<<<1, 128, 0, stream>>>(partial);
  chunk_scan_kernel<<<NBLK, 256, 0, stream>>>(cnt_in, partial, row_ptr);
  fill_lds_kernel<<<NSEG * NCHUNK, 1024, 0, stream>>>(esrc, edst, row_ptr, pin, csr_src);

  const int gb = (NN + 255) / 256;
  const int gg = (NN + 3) / 4;

  // Layer 0: m = (x*norm_out) @ W0 ; h = relu(agg*norm_in + b0)*norm_out
  gemm_kernel<128, 64, true><<<gb, 256, 0, stream>>>(x, W0, norm_out, m);
  gather_kernel<64, true><<<gg, 256, 0, stream>>>(m, row_ptr, csr_src, norm_in, norm_out, b0, h);

  // Layer 1: m = h @ W1 ; h = relu(agg*norm_in + b1)*norm_out
  gemm_kernel<64, 64, false><<<gb, 256, 0, stream>>>(h, W1, nullptr, m);
  gather_kernel<64, true><<<gg, 256, 0, stream>>>(m, row_ptr, csr_src, norm_in, norm_out, b1, h);

  // Layer 2: m = h @ W2 (40 cols) ; out = agg*norm_in + b2
  gemm_kernel<64, 40, false><<<gb, 256, 0, stream>>>(h, W2, nullptr, m);
  gather_kernel<40, false><<<gg, 256, 0, stream>>>(m, row_ptr, csr_src, norm_in, norm_out, b2, out);
}